// Round 1
// baseline (905.156 us; speedup 1.0000x reference)
//
#include <hip/hip_runtime.h>

// Pipeline_8400956031319: dual greedy NMS (8192 det + 8192 rpn, IOU>0.6,
// index order) + argmax masking.
//
// Stage 1: bitmask of suppression candidates (j>i, iou>0.6), 64x64 tiles.
// Stage 2: sequential greedy scan over rows, 1 wave per set, suppressed
//          bitvector distributed across lanes (2x u64/lane), deep prefetch.
// Stage 3: epilogue applies keep bits + score argmax to produce 3 outputs.

constexpr int   NROWS = 8192;   // boxes per set (fixed by setup_inputs)
constexpr int   NW    = 128;    // 64-bit mask words per row (8192/64)
constexpr int   PF    = 16;     // scan prefetch depth (rows in flight)
#define IOU_T 0.6f

// ---------------------------------------------------------------------------
// Stage 1: suppression bitmask. grid = (128 colblk, 128 rowblk, 2 set), 64 thr.
// masks[set][row][word] ; word bj covers cols [bj*64, bj*64+64).
// Lower-triangular blocks write 0 (ws is poisoned 0xAA before every launch).
// IOU arithmetic mirrors the reference fp32 expression exactly (division,
// same op order, no fma-contractible sites) so keep bits match bit-for-bit.
// ---------------------------------------------------------------------------
__global__ __launch_bounds__(64) void nms_mask_kernel(
    const float* __restrict__ det, const float* __restrict__ rpn,
    unsigned long long* __restrict__ masks)
{
  const int bj = blockIdx.x, bi = blockIdx.y, set = blockIdx.z;
  const int t = threadIdx.x;
  const int i = bi * 64 + t;
  unsigned long long* out = masks + ((size_t)set * NROWS + i) * NW + bj;
  if (bj < bi) { *out = 0ull; return; }

  const float* src   = (set == 0) ? det : rpn;
  const int    strd  = (set == 0) ? 9 : 6;

  __shared__ float4 cb[64];
  {
    const float* q = src + (size_t)(bj * 64 + t) * strd + 1;
    cb[t] = make_float4(q[0], q[1], q[2], q[3]);
  }
  __syncthreads();

  const float* p = src + (size_t)i * strd + 1;
  const float x1 = p[0], y1 = p[1], x2 = p[2], y2 = p[3];
  const float ai = fmaxf(x2 - x1, 0.0f) * fmaxf(y2 - y1, 0.0f);

  unsigned long long bits = 0ull;
  #pragma unroll 8
  for (int c = 0; c < 64; ++c) {
    const float4 b = cb[c];
    const float ix1 = fmaxf(x1, b.x), iy1 = fmaxf(y1, b.y);
    const float ix2 = fminf(x2, b.z), iy2 = fminf(y2, b.w);
    const float inter = fmaxf(ix2 - ix1, 0.0f) * fmaxf(iy2 - iy1, 0.0f);
    const float aj = fmaxf(b.z - b.x, 0.0f) * fmaxf(b.w - b.y, 0.0f);
    const float uni = ai + aj - inter;                 // same order as ref
    const float iou = inter / fmaxf(uni, 1e-9f);       // same expr as ref
    if (iou > IOU_T) bits |= (1ull << c);
  }
  // strictly-upper-triangular (j > i): only matters on the diagonal block
  if (bi == bj) bits = (t == 63) ? 0ull : (bits & (~0ull << (t + 1)));
  *out = bits;
}

// ---------------------------------------------------------------------------
// Stage 2: sequential greedy scan. grid = 2 blocks (one per set), 64 threads.
// Lane l holds suppressed words 2l, 2l+1 in registers (s0,s1). Bit test for
// row i via 64-bit __shfl from owner lane (wave-synchronous, NO barriers —
// keeps the PF-deep global-load pipeline alive; __syncthreads would force a
// vmcnt(0) drain every iteration). keep bits accumulated (uniform) and
// stored once per 64 rows.
// ---------------------------------------------------------------------------
__global__ __launch_bounds__(64) void nms_scan_kernel(
    const unsigned long long* __restrict__ masks,
    unsigned long long* __restrict__ keep)
{
  const int set  = blockIdx.x;
  const ulonglong2* row = (const ulonglong2*)(masks + (size_t)set * NROWS * NW);
  unsigned long long* kout = keep + set * NW;
  const int lane = threadIdx.x;

  unsigned long long s0 = 0ull, s1 = 0ull;   // suppressed words 2*lane, 2*lane+1
  ulonglong2 buf[PF];
  #pragma unroll
  for (int k = 0; k < PF; ++k) buf[k] = row[(size_t)k * 64 + lane];

  unsigned long long kw = 0ull;              // keep bits for current word (uniform)
  for (int base = 0; base < NROWS; base += PF) {
    #pragma unroll
    for (int k = 0; k < PF; ++k) {
      const int i = base + k;
      const ulonglong2 r = buf[k];
      const int nxt = i + PF;
      if (nxt < NROWS) buf[k] = row[(size_t)nxt * 64 + lane];

      const int w = i >> 6;                          // word holding bit i (uniform)
      const unsigned long long sel = (w & 1) ? s1 : s0;
      const unsigned long long word =
          __shfl((unsigned long long)sel, w >> 1);   // broadcast from owner lane
      const bool ki = ((word >> (i & 63)) & 1ull) == 0ull;   // uniform
      if (ki) { s0 |= r.x; s1 |= r.y; }
      kw |= (unsigned long long)(ki ? 1ull : 0ull) << (i & 63);
      if ((i & 63) == 63) {
        if (lane == 0) kout[w] = kw;
        kw = 0ull;
      }
    }
  }
}

// ---------------------------------------------------------------------------
// Stage 3: epilogue. One thread per row: argmax(scores 5..8, first-max like
// jnp.argmax) + keep bits -> three masked outputs.
// ---------------------------------------------------------------------------
__global__ __launch_bounds__(256) void epilogue_kernel(
    const float* __restrict__ det, const float* __restrict__ rpn,
    const unsigned long long* __restrict__ keep, float* __restrict__ out)
{
  const int i = blockIdx.x * 256 + threadIdx.x;
  if (i >= NROWS) return;
  const bool kd = (keep[i >> 6]      >> (i & 63)) & 1ull;
  const bool kr = (keep[NW + (i >> 6)] >> (i & 63)) & 1ull;

  const float* p = det + (size_t)i * 9;
  const float sc0 = p[5], sc1 = p[6], sc2 = p[7], sc3 = p[8];
  int am = 0; float best = sc0;
  if (sc1 > best) { best = sc1; am = 1; }
  if (sc2 > best) { best = sc2; am = 2; }
  if (sc3 > best) { best = sc3; am = 3; }

  const float vm = (kd && am != 0) ? 1.0f : 0.0f;
  const float im = (kd && am == 0) ? 1.0f : 0.0f;
  float* o0 = out + (size_t)i * 9;
  float* o1 = out + (size_t)NROWS * 9 + (size_t)i * 9;
  #pragma unroll
  for (int c = 0; c < 9; ++c) { const float v = p[c]; o0[c] = v * vm; o1[c] = v * im; }

  const float rm = kr ? 1.0f : 0.0f;
  const float* q = rpn + (size_t)i * 6;
  float* o2 = out + (size_t)NROWS * 18 + (size_t)i * 6;
  #pragma unroll
  for (int c = 0; c < 6; ++c) o2[c] = q[c] * rm;
}

// ---------------------------------------------------------------------------
extern "C" void kernel_launch(void* const* d_in, const int* in_sizes, int n_in,
                              void* d_out, int out_size, void* d_ws, size_t ws_size,
                              hipStream_t stream)
{
  const float* det = (const float*)d_in[0];   // 8192 x 9 fp32
  const float* rpn = (const float*)d_in[1];   // 8192 x 6 fp32
  float* out = (float*)d_out;                 // 8192*9 + 8192*9 + 8192*6 fp32

  // workspace layout: [2][8192][128] u64 masks (16 MiB) + [2][128] u64 keep
  unsigned long long* masks = (unsigned long long*)d_ws;
  unsigned long long* keep  = masks + (size_t)2 * NROWS * NW;

  dim3 g1(NW, NW, 2);
  nms_mask_kernel<<<g1, 64, 0, stream>>>(det, rpn, masks);
  nms_scan_kernel<<<2, 64, 0, stream>>>(masks, keep);
  epilogue_kernel<<<(NROWS + 255) / 256, 256, 0, stream>>>(det, rpn, keep, out);
}

// Round 2
// 709.740 us; speedup vs baseline: 1.2753x; 1.2753x over previous
//
#include <hip/hip_runtime.h>

// Pipeline_8400956031319: dual greedy NMS (8192 det + 8192 rpn, IOU>0.6,
// index order) + argmax masking.
//
// Stage 1: bitmask of suppression candidates (j>i, iou>0.6), 64x64 tiles.
// Stage 2: sequential greedy scan, block-of-64 formulation: per 64-row block,
//          resolve the intra-block dependency in SCALAR regs (readlane'd diag
//          words), then OR kept rows' full masks into lane-distributed state.
//          R0 version paid ~227 cyc/row on a 64-bit __shfl (2x ds_bpermute)
//          per row; this pays 2 readlanes per BLOCK on the chain instead.
// Stage 3: epilogue applies keep bits + score argmax to produce 3 outputs.

constexpr int   NROWS = 8192;   // boxes per set (fixed by setup_inputs)
constexpr int   NW    = 128;    // 64-bit mask words per row (8192/64)
constexpr int   NB    = 128;    // row blocks (8192/64)
constexpr int   PF    = 16;     // scan prefetch depth (rows in flight)
#define IOU_T 0.6f

__device__ __forceinline__ unsigned rl_u32(unsigned v, int lane) {
  return (unsigned)__builtin_amdgcn_readlane((int)v, lane);
}
__device__ __forceinline__ unsigned long long rl_u64(unsigned long long v, int lane) {
  unsigned lo = rl_u32((unsigned)v, lane);
  unsigned hi = rl_u32((unsigned)(v >> 32), lane);
  return ((unsigned long long)hi << 32) | lo;
}

// ---------------------------------------------------------------------------
// Stage 1: suppression bitmask. grid = (128 colblk, 128 rowblk, 2 set), 64 thr.
// masks[set][row][word] ; word bj covers cols [bj*64, bj*64+64).
// Lower-triangular blocks write 0 (ws is poisoned 0xAA before every launch).
// IOU arithmetic mirrors the reference fp32 expression exactly (division,
// same op order, no fma-contractible sites) so keep bits match bit-for-bit.
// ---------------------------------------------------------------------------
__global__ __launch_bounds__(64) void nms_mask_kernel(
    const float* __restrict__ det, const float* __restrict__ rpn,
    unsigned long long* __restrict__ masks)
{
  const int bj = blockIdx.x, bi = blockIdx.y, set = blockIdx.z;
  const int t = threadIdx.x;
  const int i = bi * 64 + t;
  unsigned long long* out = masks + ((size_t)set * NROWS + i) * NW + bj;
  if (bj < bi) { *out = 0ull; return; }

  const float* src   = (set == 0) ? det : rpn;
  const int    strd  = (set == 0) ? 9 : 6;

  __shared__ float4 cb[64];
  {
    const float* q = src + (size_t)(bj * 64 + t) * strd + 1;
    cb[t] = make_float4(q[0], q[1], q[2], q[3]);
  }
  __syncthreads();

  const float* p = src + (size_t)i * strd + 1;
  const float x1 = p[0], y1 = p[1], x2 = p[2], y2 = p[3];
  const float ai = fmaxf(x2 - x1, 0.0f) * fmaxf(y2 - y1, 0.0f);

  unsigned long long bits = 0ull;
  #pragma unroll 8
  for (int c = 0; c < 64; ++c) {
    const float4 b = cb[c];
    const float ix1 = fmaxf(x1, b.x), iy1 = fmaxf(y1, b.y);
    const float ix2 = fminf(x2, b.z), iy2 = fminf(y2, b.w);
    const float inter = fmaxf(ix2 - ix1, 0.0f) * fmaxf(iy2 - iy1, 0.0f);
    const float aj = fmaxf(b.z - b.x, 0.0f) * fmaxf(b.w - b.y, 0.0f);
    const float uni = ai + aj - inter;                 // same order as ref
    const float iou = inter / fmaxf(uni, 1e-9f);       // same expr as ref
    if (iou > IOU_T) bits |= (1ull << c);
  }
  // strictly-upper-triangular (j > i): only matters on the diagonal block
  if (bi == bj) bits = (t == 63) ? 0ull : (bits & (~0ull << (t + 1)));
  *out = bits;
}

// ---------------------------------------------------------------------------
// Stage 2: greedy scan, 1 wave per set. Lane l holds suppressed column-words
// 2l, 2l+1 (s0,s1). Per 64-row block b:
//   - cur = state word b (2 readlanes from owner lane — once per block)
//   - diag[i] = masks[64b+i][b] (lane i holds row 64b+i's diag word,
//     prefetched one block ahead); resolve 64 rows scalar: test bit i of cur,
//     if kept: kw |= bit, cur |= readlane(diag, i)
//   - OR phase: stream rows (PF-deep coalesced ulonglong2 prefetch), uniform
//     scalar branch skips suppressed rows' ORs (~70% of rows).
// No barriers anywhere — single wave, wave-synchronous.
// ---------------------------------------------------------------------------
__global__ __launch_bounds__(64) void nms_scan_kernel(
    const unsigned long long* __restrict__ masks,
    unsigned long long* __restrict__ keep)
{
  const int set  = blockIdx.x;
  const unsigned long long* mrow = masks + (size_t)set * NROWS * NW;
  const ulonglong2* row = (const ulonglong2*)mrow;
  unsigned long long* kout = keep + set * NW;
  const int lane = threadIdx.x;

  unsigned long long s0 = 0ull, s1 = 0ull;   // suppressed cols 2*lane, 2*lane+1

  // row-data prefetch: buf[k] holds words [2*lane, 2*lane+1] of row k
  ulonglong2 buf[PF];
  #pragma unroll
  for (int k = 0; k < PF; ++k) buf[k] = row[(size_t)k * 64 + lane];

  // diag prefetch for block 0: lane l -> masks[l][0]
  unsigned long long diag = mrow[(size_t)lane * NW + 0];

  for (int b = 0; b < NB; ++b) {
    // issue next block's diag load early (latency hidden under this block)
    unsigned long long diag_next = 0ull;
    if (b + 1 < NB)
      diag_next = mrow[(size_t)(64 * (b + 1) + lane) * NW + (b + 1)];

    // fetch current suppressed word for this block (owner lane b>>1)
    const unsigned long long selw = (b & 1) ? s1 : s0;
    unsigned long long cur = rl_u64(selw, b >> 1);

    // scalar resolve of the 64-row intra-block dependency
    unsigned long long kw = 0ull;
    #pragma unroll
    for (int i = 0; i < 64; ++i) {
      const unsigned long long d = rl_u64(diag, i);    // const-lane readlane
      if (!((cur >> i) & 1ull)) {                      // uniform scalar branch
        kw  |= (1ull << i);
        cur |= d;
      }
    }
    if (lane == 0) kout[b] = kw;

    // OR phase: accumulate kept rows' full masks into distributed state
    #pragma unroll
    for (int i = 0; i < 64; ++i) {
      const int slot = i & (PF - 1);                   // static after unroll
      const ulonglong2 r = buf[slot];
      const int nxt = 64 * b + i + PF;
      if (nxt < NROWS) buf[slot] = row[(size_t)nxt * 64 + lane];
      if ((kw >> i) & 1ull) {                          // uniform: skip suppressed
        s0 |= r.x; s1 |= r.y;
      }
    }

    diag = diag_next;
  }
}

// ---------------------------------------------------------------------------
// Stage 3: epilogue. One thread per row: argmax(scores 5..8, first-max like
// jnp.argmax) + keep bits -> three masked outputs.
// ---------------------------------------------------------------------------
__global__ __launch_bounds__(256) void epilogue_kernel(
    const float* __restrict__ det, const float* __restrict__ rpn,
    const unsigned long long* __restrict__ keep, float* __restrict__ out)
{
  const int i = blockIdx.x * 256 + threadIdx.x;
  if (i >= NROWS) return;
  const bool kd = (keep[i >> 6]        >> (i & 63)) & 1ull;
  const bool kr = (keep[NW + (i >> 6)] >> (i & 63)) & 1ull;

  const float* p = det + (size_t)i * 9;
  const float sc0 = p[5], sc1 = p[6], sc2 = p[7], sc3 = p[8];
  int am = 0; float best = sc0;
  if (sc1 > best) { best = sc1; am = 1; }
  if (sc2 > best) { best = sc2; am = 2; }
  if (sc3 > best) { best = sc3; am = 3; }

  const float vm = (kd && am != 0) ? 1.0f : 0.0f;
  const float im = (kd && am == 0) ? 1.0f : 0.0f;
  float* o0 = out + (size_t)i * 9;
  float* o1 = out + (size_t)NROWS * 9 + (size_t)i * 9;
  #pragma unroll
  for (int c = 0; c < 9; ++c) { const float v = p[c]; o0[c] = v * vm; o1[c] = v * im; }

  const float rm = kr ? 1.0f : 0.0f;
  const float* q = rpn + (size_t)i * 6;
  float* o2 = out + (size_t)NROWS * 18 + (size_t)i * 6;
  #pragma unroll
  for (int c = 0; c < 6; ++c) o2[c] = q[c] * rm;
}

// ---------------------------------------------------------------------------
extern "C" void kernel_launch(void* const* d_in, const int* in_sizes, int n_in,
                              void* d_out, int out_size, void* d_ws, size_t ws_size,
                              hipStream_t stream)
{
  const float* det = (const float*)d_in[0];   // 8192 x 9 fp32
  const float* rpn = (const float*)d_in[1];   // 8192 x 6 fp32
  float* out = (float*)d_out;                 // 8192*9 + 8192*9 + 8192*6 fp32

  // workspace layout: [2][8192][128] u64 masks (16 MiB) + [2][128] u64 keep
  unsigned long long* masks = (unsigned long long*)d_ws;
  unsigned long long* keep  = masks + (size_t)2 * NROWS * NW;

  dim3 g1(NW, NW, 2);
  nms_mask_kernel<<<g1, 64, 0, stream>>>(det, rpn, masks);
  nms_scan_kernel<<<2, 64, 0, stream>>>(masks, keep);
  epilogue_kernel<<<(NROWS + 255) / 256, 256, 0, stream>>>(det, rpn, keep, out);
}

// Round 3
// 283.466 us; speedup vs baseline: 3.1932x; 2.5038x over previous
//
#include <hip/hip_runtime.h>

// Pipeline_8400956031319: dual greedy NMS (8192 det + 8192 rpn, IOU>0.6,
// index order) + argmax masking.
//
// Stage 1: bitmask of suppression candidates (j>i, iou>0.6), 64x64 tiles,
//          upper-triangular blocks only (lower-tri never read).
// Stage 2: greedy scan, ONE 1024-thread workgroup per set (16 waves).
//          Suppressed bitvector (128 u64) lives in LDS. Per 64-row block:
//          wave0 resolves the serial intra-block dependency (ballot-pruned
//          ctz loop, ~few iterations); all 16 waves OR kept rows' masks into
//          LDS state (ds_or_b64), with row data prefetched 2 blocks ahead in
//          registers. R2's single-wave version was latency-bound at ~125
//          cyc/row (16 outstanding loads vs ~2000 cyc memory latency); this
//          gets MLP from 16 waves x 8 static-address loads.
// Stage 3: epilogue applies keep bits + score argmax to produce 3 outputs.

constexpr int   NROWS = 8192;   // boxes per set (fixed by setup_inputs)
constexpr int   NW    = 128;    // 64-bit mask words per row (8192/64)
constexpr int   NB    = 128;    // row blocks (8192/64)
#define IOU_T 0.6f

__device__ __forceinline__ unsigned long long rfl64(unsigned long long v) {
  unsigned lo = (unsigned)__builtin_amdgcn_readfirstlane((int)(unsigned)v);
  unsigned hi = (unsigned)__builtin_amdgcn_readfirstlane((int)(unsigned)(v >> 32));
  return ((unsigned long long)hi << 32) | lo;
}
__device__ __forceinline__ unsigned long long rl64_dyn(unsigned long long v, int lane) {
  unsigned lo = (unsigned)__builtin_amdgcn_readlane((int)(unsigned)v, lane);
  unsigned hi = (unsigned)__builtin_amdgcn_readlane((int)(unsigned)(v >> 32), lane);
  return ((unsigned long long)hi << 32) | lo;
}

// ---------------------------------------------------------------------------
// Stage 1: suppression bitmask. grid = (128 colblk, 128 rowblk, 2 set), 64 thr.
// masks[set][row][word]; word bj covers cols [bj*64, bj*64+64).
// Lower-triangular blocks are SKIPPED (scan only reads w >= row-block).
// IOU arithmetic mirrors the reference fp32 expression exactly (division,
// same op order, no fma-contractible sites) so keep bits match bit-for-bit.
// ---------------------------------------------------------------------------
__global__ __launch_bounds__(64) void nms_mask_kernel(
    const float* __restrict__ det, const float* __restrict__ rpn,
    unsigned long long* __restrict__ masks)
{
  const int bj = blockIdx.x, bi = blockIdx.y, set = blockIdx.z;
  if (bj < bi) return;                       // never read by the scan
  const int t = threadIdx.x;
  const int i = bi * 64 + t;

  const float* src   = (set == 0) ? det : rpn;
  const int    strd  = (set == 0) ? 9 : 6;

  __shared__ float4 cb[64];
  {
    const float* q = src + (size_t)(bj * 64 + t) * strd + 1;
    cb[t] = make_float4(q[0], q[1], q[2], q[3]);
  }
  __syncthreads();

  const float* p = src + (size_t)i * strd + 1;
  const float x1 = p[0], y1 = p[1], x2 = p[2], y2 = p[3];
  const float ai = fmaxf(x2 - x1, 0.0f) * fmaxf(y2 - y1, 0.0f);

  unsigned long long bits = 0ull;
  #pragma unroll 8
  for (int c = 0; c < 64; ++c) {
    const float4 b = cb[c];
    const float ix1 = fmaxf(x1, b.x), iy1 = fmaxf(y1, b.y);
    const float ix2 = fminf(x2, b.z), iy2 = fminf(y2, b.w);
    const float inter = fmaxf(ix2 - ix1, 0.0f) * fmaxf(iy2 - iy1, 0.0f);
    const float aj = fmaxf(b.z - b.x, 0.0f) * fmaxf(b.w - b.y, 0.0f);
    const float uni = ai + aj - inter;                 // same order as ref
    const float iou = inter / fmaxf(uni, 1e-9f);       // same expr as ref
    if (iou > IOU_T) bits |= (1ull << c);
  }
  // strictly-upper-triangular (j > i): only matters on the diagonal block
  if (bi == bj) bits = (t == 63) ? 0ull : (bits & (~0ull << (t + 1)));
  masks[((size_t)set * NROWS + i) * NW + bj] = bits;
}

// ---------------------------------------------------------------------------
// Stage 2: greedy scan. grid = 2 workgroups (one per set) x 1024 threads.
// Thread t: column word w = t&127, row subgroup g = t>>7 (rows g*8..g*8+7 of
// each block). sup[w] in LDS is the suppressed bitvector. Row-mask loads are
// static addresses -> prefetched 2 blocks ahead into 4 rotating reg buffers.
// Wave 0 additionally prefetches diag words (lane i <- masks[64b+i][b]) and
// runs the serial resolve: ballot(d!=0) prunes the ctz loop to only kept rows
// that actually suppress within the block.
// ---------------------------------------------------------------------------
__global__ __launch_bounds__(1024) void nms_scan_kernel(
    const unsigned long long* __restrict__ masks,
    unsigned long long* __restrict__ keep)
{
  const int set = blockIdx.x;
  const unsigned long long* m = masks + (size_t)set * NROWS * NW;
  unsigned long long* kout = keep + set * NW;

  __shared__ unsigned long long sup[NW];
  __shared__ unsigned long long kw_sh;

  const int t = threadIdx.x;
  const int w = t & 127;        // column word owned
  const int g = t >> 7;         // row subgroup (8 rows/block)
  const int lane = t & 63;
  const bool wave0 = (t < 64);

  if (t < NW) sup[t] = 0ull;

  // diag prefetch (wave0): d0 = block 0, d1 = block 1
  unsigned long long d0 = 0ull, d1 = 0ull;
  if (wave0) {
    d0 = m[(size_t)(0 * 64 + lane) * NW + 0];
    d1 = m[(size_t)(1 * 64 + lane) * NW + 1];
  }

  // row buffers: 4 rotating, each holds this thread's 8 rows of one block
  unsigned long long buf0[8], buf1[8], buf2[8], buf3[8];
  if (w > 0) {
    #pragma unroll
    for (int k = 0; k < 8; ++k) buf0[k] = m[(size_t)(0 * 64 + g * 8 + k) * NW + w];
  }
  if (w > 1) {
    #pragma unroll
    for (int k = 0; k < 8; ++k) buf1[k] = m[(size_t)(1 * 64 + g * 8 + k) * NW + w];
  }

  __syncthreads();

#define SCAN_STEP(B, CONS, FILL)                                              \
  {                                                                           \
    const int b  = (B);                                                       \
    const int bb = b + 2;                                                     \
    if (bb < NB && w > bb) {                                                  \
      _Pragma("unroll")                                                       \
      for (int k = 0; k < 8; ++k)                                             \
        FILL[k] = m[(size_t)(bb * 64 + g * 8 + k) * NW + w];                  \
    }                                                                         \
    if (wave0) {                                                              \
      unsigned long long dn = 0ull;                                           \
      if (bb < NB) dn = m[(size_t)(bb * 64 + lane) * NW + bb];                \
      unsigned long long cur   = rfl64(sup[b]);                               \
      const unsigned long long nz = __ballot(d0 != 0ull);                     \
      unsigned long long alive = ~cur, kw = 0ull;                             \
      while (true) {                                                          \
        const unsigned long long cand = alive & nz;                           \
        if (!cand) { kw |= alive; break; }                                    \
        const int ii = __builtin_ctzll(cand);                                 \
        const unsigned long long bit = 1ull << ii;                            \
        kw |= (alive & (bit - 1ull)) | bit;                                   \
        const unsigned long long d = rl64_dyn(d0, ii);                        \
        alive &= ~(d | bit | (bit - 1ull));                                   \
      }                                                                       \
      if (lane == 0) { kw_sh = kw; kout[b] = kw; }                            \
      d0 = d1; d1 = dn;                                                       \
    }                                                                         \
    __syncthreads();                                                          \
    const unsigned long long kwv = kw_sh;                                     \
    if (w > b) {                                                              \
      unsigned long long acc = 0ull;                                          \
      _Pragma("unroll")                                                       \
      for (int k = 0; k < 8; ++k)                                             \
        if ((kwv >> (g * 8 + k)) & 1ull) acc |= CONS[k];                      \
      if (acc) atomicOr(&sup[w], acc);                                        \
    }                                                                         \
    __syncthreads();                                                          \
  }

  for (int b4 = 0; b4 < NB; b4 += 4) {
    SCAN_STEP(b4 + 0, buf0, buf2)
    SCAN_STEP(b4 + 1, buf1, buf3)
    SCAN_STEP(b4 + 2, buf2, buf0)
    SCAN_STEP(b4 + 3, buf3, buf1)
  }
#undef SCAN_STEP
}

// ---------------------------------------------------------------------------
// Stage 3: epilogue. One thread per row: argmax(scores 5..8, first-max like
// jnp.argmax) + keep bits -> three masked outputs.
// ---------------------------------------------------------------------------
__global__ __launch_bounds__(256) void epilogue_kernel(
    const float* __restrict__ det, const float* __restrict__ rpn,
    const unsigned long long* __restrict__ keep, float* __restrict__ out)
{
  const int i = blockIdx.x * 256 + threadIdx.x;
  if (i >= NROWS) return;
  const bool kd = (keep[i >> 6]        >> (i & 63)) & 1ull;
  const bool kr = (keep[NW + (i >> 6)] >> (i & 63)) & 1ull;

  const float* p = det + (size_t)i * 9;
  const float sc0 = p[5], sc1 = p[6], sc2 = p[7], sc3 = p[8];
  int am = 0; float best = sc0;
  if (sc1 > best) { best = sc1; am = 1; }
  if (sc2 > best) { best = sc2; am = 2; }
  if (sc3 > best) { best = sc3; am = 3; }

  const float vm = (kd && am != 0) ? 1.0f : 0.0f;
  const float im = (kd && am == 0) ? 1.0f : 0.0f;
  float* o0 = out + (size_t)i * 9;
  float* o1 = out + (size_t)NROWS * 9 + (size_t)i * 9;
  #pragma unroll
  for (int c = 0; c < 9; ++c) { const float v = p[c]; o0[c] = v * vm; o1[c] = v * im; }

  const float rm = kr ? 1.0f : 0.0f;
  const float* q = rpn + (size_t)i * 6;
  float* o2 = out + (size_t)NROWS * 18 + (size_t)i * 6;
  #pragma unroll
  for (int c = 0; c < 6; ++c) o2[c] = q[c] * rm;
}

// ---------------------------------------------------------------------------
extern "C" void kernel_launch(void* const* d_in, const int* in_sizes, int n_in,
                              void* d_out, int out_size, void* d_ws, size_t ws_size,
                              hipStream_t stream)
{
  const float* det = (const float*)d_in[0];   // 8192 x 9 fp32
  const float* rpn = (const float*)d_in[1];   // 8192 x 6 fp32
  float* out = (float*)d_out;                 // 8192*9 + 8192*9 + 8192*6 fp32

  // workspace layout: [2][8192][128] u64 masks (16 MiB) + [2][128] u64 keep
  unsigned long long* masks = (unsigned long long*)d_ws;
  unsigned long long* keep  = masks + (size_t)2 * NROWS * NW;

  dim3 g1(NW, NW, 2);
  nms_mask_kernel<<<g1, 64, 0, stream>>>(det, rpn, masks);
  nms_scan_kernel<<<2, 1024, 0, stream>>>(masks, keep);
  epilogue_kernel<<<(NROWS + 255) / 256, 256, 0, stream>>>(det, rpn, keep, out);
}

// Round 4
// 264.100 us; speedup vs baseline: 3.4273x; 1.0733x over previous
//
#include <hip/hip_runtime.h>

// Pipeline_8400956031319: dual greedy NMS (8192 det + 8192 rpn, IOU>0.6,
// index order) + argmax masking.
//
// Stage 1: bitmask of suppression candidates (j>i, iou>0.6), 64x64 tiles
//          (4 row-tiles per 256-thread block), upper-triangular only,
//          overlap-pruned (div only when some lane has inter>0).
// Stage 2: greedy scan, one 1024-thread workgroup per set. Suppressed
//          bitvector in LDS. KEY FIX vs R2: __syncthreads makes the compiler
//          emit s_waitcnt vmcnt(0) before s_barrier, draining the global
//          prefetch queue every block (~exposed LLC latency per block).
//          Replaced with raw `s_waitcnt lgkmcnt(0); s_barrier` so prefetch
//          loads stay in flight across barriers; 3 rotating reg buffers,
//          distance-2 prefetch.
// Stage 3: epilogue applies keep bits + score argmax to produce 3 outputs.

constexpr int   NROWS = 8192;   // boxes per set (fixed by setup_inputs)
constexpr int   NW    = 128;    // 64-bit mask words per row (8192/64)
constexpr int   NB    = 128;    // row blocks (8192/64)
#define IOU_T 0.6f

__device__ __forceinline__ unsigned long long rfl64(unsigned long long v) {
  unsigned lo = (unsigned)__builtin_amdgcn_readfirstlane((int)(unsigned)v);
  unsigned hi = (unsigned)__builtin_amdgcn_readfirstlane((int)(unsigned)(v >> 32));
  return ((unsigned long long)hi << 32) | lo;
}
__device__ __forceinline__ unsigned long long rl64_dyn(unsigned long long v, int lane) {
  unsigned lo = (unsigned)__builtin_amdgcn_readlane((int)(unsigned)v, lane);
  unsigned hi = (unsigned)__builtin_amdgcn_readlane((int)(unsigned)(v >> 32), lane);
  return ((unsigned long long)hi << 32) | lo;
}
// Barrier that waits ONLY on LDS ops (lgkmcnt), NOT vmcnt: keeps global
// prefetch loads in flight across the barrier. All inter-wave data exchange
// in the scan goes through LDS, so lgkmcnt(0) is sufficient for visibility.
__device__ __forceinline__ void wg_barrier_lds() {
  asm volatile("s_waitcnt lgkmcnt(0)\n\ts_barrier" ::: "memory");
}

// ---------------------------------------------------------------------------
// Stage 1: suppression bitmask. grid = (128 colblk, 32 rowblk4, 2 set),
// 256 threads = 4 row-waves sharing one 64-col tile in LDS.
// masks[set][row][word]; word bj covers cols [bj*64, bj*64+64).
// Lower-triangular blocks skipped (never read by the scan).
// IOU arithmetic mirrors the reference fp32 expression exactly (IEEE div,
// same op order) so keep bits match bit-for-bit. Overlap pruning is exact:
// inter==0 -> iou==0 -> bit clear, identical to the reference.
// ---------------------------------------------------------------------------
__global__ __launch_bounds__(256) void nms_mask_kernel(
    const float* __restrict__ det, const float* __restrict__ rpn,
    unsigned long long* __restrict__ masks)
{
  const int bj = blockIdx.x, bi4 = blockIdx.y, set = blockIdx.z;
  if (bj < bi4 * 4) return;                 // whole block lower-triangular
  const int t = threadIdx.x;
  const int wv = t >> 6, lane = t & 63;
  const int bi = bi4 * 4 + wv;

  const float* src  = (set == 0) ? det : rpn;
  const int    strd = (set == 0) ? 9 : 6;

  __shared__ float4 cb[64];
  __shared__ float  cbA[64];
  if (t < 64) {
    const float* q = src + (size_t)(bj * 64 + t) * strd + 1;
    const float4 v = make_float4(q[0], q[1], q[2], q[3]);
    cb[t]  = v;
    cbA[t] = fmaxf(v.z - v.x, 0.0f) * fmaxf(v.w - v.y, 0.0f);
  }
  __syncthreads();
  if (bj < bi) return;                      // wave-uniform partial skip

  const int i = bi * 64 + lane;
  const float* p = src + (size_t)i * strd + 1;
  const float x1 = p[0], y1 = p[1], x2 = p[2], y2 = p[3];
  const float ai = fmaxf(x2 - x1, 0.0f) * fmaxf(y2 - y1, 0.0f);

  unsigned long long bits = 0ull;
  #pragma unroll 4
  for (int c = 0; c < 64; ++c) {
    const float4 b = cb[c];
    const float ix1 = fmaxf(x1, b.x), iy1 = fmaxf(y1, b.y);
    const float ix2 = fminf(x2, b.z), iy2 = fminf(y2, b.w);
    const float inter = fmaxf(ix2 - ix1, 0.0f) * fmaxf(iy2 - iy1, 0.0f);
    if (__any(inter > 0.0f)) {              // ~75-80% of columns skip the div
      const float uni = ai + cbA[c] - inter;           // same order as ref
      const float iou = inter / fmaxf(uni, 1e-9f);     // same expr as ref
      if (iou > IOU_T) bits |= (1ull << c);
    }
  }
  // strictly-upper-triangular (j > i): only matters on the diagonal block
  if (bi == bj) bits = (lane == 63) ? 0ull : (bits & (~0ull << (lane + 1)));
  masks[((size_t)set * NROWS + i) * NW + bj] = bits;
}

// ---------------------------------------------------------------------------
// Stage 2: greedy scan. grid = 2 workgroups (one per set) x 1024 threads.
// Thread t: column word w = t&127, row subgroup g = t>>7 (8 rows/block).
// sup[w] in LDS is the suppressed bitvector. Row-mask loads prefetched 2
// blocks ahead into 3 rotating reg buffers (48 VGPRs). Wave 0 prefetches
// diag words (lane i <- masks[64b+i][b]) and runs the serial resolve
// (ballot-pruned ctz loop). All barriers are lgkmcnt-only.
// ---------------------------------------------------------------------------
__global__ __launch_bounds__(1024) void nms_scan_kernel(
    const unsigned long long* __restrict__ masks,
    unsigned long long* __restrict__ keep)
{
  const int set = blockIdx.x;
  const unsigned long long* m = masks + (size_t)set * NROWS * NW;
  unsigned long long* kout = keep + set * NW;

  __shared__ unsigned long long sup[NW];
  __shared__ unsigned long long kw_sh;

  const int t = threadIdx.x;
  const int w = t & 127;        // column word owned
  const int g = t >> 7;         // row subgroup (8 rows/block)
  const int lane = t & 63;
  const bool wave0 = (t < 64);

  if (t < NW) sup[t] = 0ull;

  // diag prefetch (wave0): d0 = block 0, d1 = block 1
  unsigned long long d0 = 0ull, d1 = 0ull;
  if (wave0) {
    d0 = m[(size_t)(0 * 64 + lane) * NW + 0];
    d1 = m[(size_t)(1 * 64 + lane) * NW + 1];
  }

  // 3 rotating buffers, distance-2 prefetch; each holds this thread's
  // 8 rows (g*8..g*8+7) x column word w of one block.
  unsigned long long bufA[8], bufB[8], bufC[8];
  if (w > 0) {
    #pragma unroll
    for (int k = 0; k < 8; ++k) bufA[k] = m[(size_t)(0 * 64 + g * 8 + k) * NW + w];
  }
  if (w > 1) {
    #pragma unroll
    for (int k = 0; k < 8; ++k) bufB[k] = m[(size_t)(1 * 64 + g * 8 + k) * NW + w];
  }

  wg_barrier_lds();

#define SCAN_STEP(B, CONS, FILL)                                              \
  {                                                                           \
    const int b = (B);                                                        \
    if (b < NB) {                                                             \
      const int bb = b + 2;                                                   \
      if (bb < NB && w > bb) {                                                \
        _Pragma("unroll")                                                     \
        for (int k = 0; k < 8; ++k)                                           \
          FILL[k] = m[(size_t)(bb * 64 + g * 8 + k) * NW + w];                \
      }                                                                       \
      if (wave0) {                                                            \
        unsigned long long dn = 0ull;                                         \
        if (bb < NB) dn = m[(size_t)(bb * 64 + lane) * NW + bb];              \
        unsigned long long cur = rfl64(sup[b]);                               \
        const unsigned long long nz = __ballot(d0 != 0ull);                   \
        unsigned long long alive = ~cur, kw = 0ull;                           \
        while (true) {                                                        \
          const unsigned long long cand = alive & nz;                         \
          if (!cand) { kw |= alive; break; }                                  \
          const int ii = __builtin_ctzll(cand);                               \
          const unsigned long long bit = 1ull << ii;                          \
          kw |= (alive & (bit - 1ull)) | bit;                                 \
          const unsigned long long d = rl64_dyn(d0, ii);                      \
          alive &= ~(d | bit | (bit - 1ull));                                 \
        }                                                                     \
        if (lane == 0) { kw_sh = kw; kout[b] = kw; }                          \
        d0 = d1; d1 = dn;                                                     \
      }                                                                       \
      wg_barrier_lds();                                                       \
      const unsigned long long kwv = kw_sh;                                   \
      if (w > b) {                                                            \
        unsigned long long acc = 0ull;                                        \
        _Pragma("unroll")                                                     \
        for (int k = 0; k < 8; ++k)                                           \
          if ((kwv >> (g * 8 + k)) & 1ull) acc |= CONS[k];                    \
        if (acc) atomicOr(&sup[w], acc);                                      \
      }                                                                       \
      wg_barrier_lds();                                                       \
    }                                                                         \
  }

  for (int b3 = 0; b3 < NB; b3 += 3) {
    SCAN_STEP(b3 + 0, bufA, bufC)
    SCAN_STEP(b3 + 1, bufB, bufA)
    SCAN_STEP(b3 + 2, bufC, bufB)
  }
#undef SCAN_STEP
}

// ---------------------------------------------------------------------------
// Stage 3: epilogue. One thread per row: argmax(scores 5..8, first-max like
// jnp.argmax) + keep bits -> three masked outputs.
// ---------------------------------------------------------------------------
__global__ __launch_bounds__(256) void epilogue_kernel(
    const float* __restrict__ det, const float* __restrict__ rpn,
    const unsigned long long* __restrict__ keep, float* __restrict__ out)
{
  const int i = blockIdx.x * 256 + threadIdx.x;
  if (i >= NROWS) return;
  const bool kd = (keep[i >> 6]        >> (i & 63)) & 1ull;
  const bool kr = (keep[NW + (i >> 6)] >> (i & 63)) & 1ull;

  const float* p = det + (size_t)i * 9;
  const float sc0 = p[5], sc1 = p[6], sc2 = p[7], sc3 = p[8];
  int am = 0; float best = sc0;
  if (sc1 > best) { best = sc1; am = 1; }
  if (sc2 > best) { best = sc2; am = 2; }
  if (sc3 > best) { best = sc3; am = 3; }

  const float vm = (kd && am != 0) ? 1.0f : 0.0f;
  const float im = (kd && am == 0) ? 1.0f : 0.0f;
  float* o0 = out + (size_t)i * 9;
  float* o1 = out + (size_t)NROWS * 9 + (size_t)i * 9;
  #pragma unroll
  for (int c = 0; c < 9; ++c) { const float v = p[c]; o0[c] = v * vm; o1[c] = v * im; }

  const float rm = kr ? 1.0f : 0.0f;
  const float* q = rpn + (size_t)i * 6;
  float* o2 = out + (size_t)NROWS * 18 + (size_t)i * 6;
  #pragma unroll
  for (int c = 0; c < 6; ++c) o2[c] = q[c] * rm;
}

// ---------------------------------------------------------------------------
extern "C" void kernel_launch(void* const* d_in, const int* in_sizes, int n_in,
                              void* d_out, int out_size, void* d_ws, size_t ws_size,
                              hipStream_t stream)
{
  const float* det = (const float*)d_in[0];   // 8192 x 9 fp32
  const float* rpn = (const float*)d_in[1];   // 8192 x 6 fp32
  float* out = (float*)d_out;                 // 8192*9 + 8192*9 + 8192*6 fp32

  // workspace layout: [2][8192][128] u64 masks (16 MiB) + [2][128] u64 keep
  unsigned long long* masks = (unsigned long long*)d_ws;
  unsigned long long* keep  = masks + (size_t)2 * NROWS * NW;

  dim3 g1(NW, NW / 4, 2);
  nms_mask_kernel<<<g1, 256, 0, stream>>>(det, rpn, masks);
  nms_scan_kernel<<<2, 1024, 0, stream>>>(masks, keep);
  epilogue_kernel<<<(NROWS + 255) / 256, 256, 0, stream>>>(det, rpn, keep, out);
}

// Round 5
// 257.720 us; speedup vs baseline: 3.5122x; 1.0248x over previous
//
#include <hip/hip_runtime.h>

// Pipeline_8400956031319: dual greedy NMS (8192 det + 8192 rpn, IOU>0.6,
// index order) + argmax masking.
//
// Stage 1: bitmask of suppression candidates (j>i, iou>0.6), 64x64 tiles
//          (4 row-tiles per 256-thread block), upper-triangular only,
//          overlap-pruned (div only when some lane has inter>0).
// Stage 2: greedy scan, one 1024-thread workgroup per set, SINGLE barrier
//          per 64-row step (R4 had 2 + resolve->OR on the critical path):
//          at step b, waves OR kept(b-1) into words w>b while wave0
//          concurrently resolves block b, reconstructing block b-1's
//          word-b contribution from a readlane'd superdiag vector.
//          kw_sh is 2-slot parity buffered. lgkmcnt-only barriers keep
//          global prefetch (distance-3, 4 rotating reg buffers) in flight.
// Stage 3: epilogue applies keep bits + score argmax to produce 3 outputs.

constexpr int   NROWS = 8192;   // boxes per set (fixed by setup_inputs)
constexpr int   NW    = 128;    // 64-bit mask words per row (8192/64)
constexpr int   NB    = 128;    // row blocks (8192/64)
#define IOU_T 0.6f

__device__ __forceinline__ unsigned long long rfl64(unsigned long long v) {
  unsigned lo = (unsigned)__builtin_amdgcn_readfirstlane((int)(unsigned)v);
  unsigned hi = (unsigned)__builtin_amdgcn_readfirstlane((int)(unsigned)(v >> 32));
  return ((unsigned long long)hi << 32) | lo;
}
__device__ __forceinline__ unsigned long long rl64_dyn(unsigned long long v, int lane) {
  unsigned lo = (unsigned)__builtin_amdgcn_readlane((int)(unsigned)v, lane);
  unsigned hi = (unsigned)__builtin_amdgcn_readlane((int)(unsigned)(v >> 32), lane);
  return ((unsigned long long)hi << 32) | lo;
}
// Barrier waiting ONLY on LDS ops (lgkmcnt), not vmcnt: global prefetch
// loads stay in flight across the barrier. All inter-wave exchange in the
// scan goes through LDS, so lgkmcnt(0) is sufficient for visibility.
__device__ __forceinline__ void wg_barrier_lds() {
  asm volatile("s_waitcnt lgkmcnt(0)\n\ts_barrier" ::: "memory");
}

// ---------------------------------------------------------------------------
// Stage 1: suppression bitmask. grid = (128 colblk, 32 rowblk4, 2 set),
// 256 threads = 4 row-waves sharing one 64-col tile in LDS.
// masks[set][row][word]; word bj covers cols [bj*64, bj*64+64).
// Lower-triangular blocks skipped (never read by the scan).
// IOU arithmetic mirrors the reference fp32 expression exactly (IEEE div,
// same op order) so keep bits match bit-for-bit. Overlap pruning is exact:
// inter==0 -> iou==0 -> bit clear, identical to the reference.
// ---------------------------------------------------------------------------
__global__ __launch_bounds__(256) void nms_mask_kernel(
    const float* __restrict__ det, const float* __restrict__ rpn,
    unsigned long long* __restrict__ masks)
{
  const int bj = blockIdx.x, bi4 = blockIdx.y, set = blockIdx.z;
  if (bj < bi4 * 4) return;                 // whole block lower-triangular
  const int t = threadIdx.x;
  const int wv = t >> 6, lane = t & 63;
  const int bi = bi4 * 4 + wv;

  const float* src  = (set == 0) ? det : rpn;
  const int    strd = (set == 0) ? 9 : 6;

  __shared__ float4 cb[64];
  __shared__ float  cbA[64];
  if (t < 64) {
    const float* q = src + (size_t)(bj * 64 + t) * strd + 1;
    const float4 v = make_float4(q[0], q[1], q[2], q[3]);
    cb[t]  = v;
    cbA[t] = fmaxf(v.z - v.x, 0.0f) * fmaxf(v.w - v.y, 0.0f);
  }
  __syncthreads();
  if (bj < bi) return;                      // wave-uniform partial skip

  const int i = bi * 64 + lane;
  const float* p = src + (size_t)i * strd + 1;
  const float x1 = p[0], y1 = p[1], x2 = p[2], y2 = p[3];
  const float ai = fmaxf(x2 - x1, 0.0f) * fmaxf(y2 - y1, 0.0f);

  unsigned long long bits = 0ull;
  #pragma unroll 4
  for (int c = 0; c < 64; ++c) {
    const float4 b = cb[c];
    const float ix1 = fmaxf(x1, b.x), iy1 = fmaxf(y1, b.y);
    const float ix2 = fminf(x2, b.z), iy2 = fminf(y2, b.w);
    const float inter = fmaxf(ix2 - ix1, 0.0f) * fmaxf(iy2 - iy1, 0.0f);
    if (__any(inter > 0.0f)) {              // ~75-80% of columns skip the div
      const float uni = ai + cbA[c] - inter;           // same order as ref
      const float iou = inter / fmaxf(uni, 1e-9f);     // same expr as ref
      if (iou > IOU_T) bits |= (1ull << c);
    }
  }
  // strictly-upper-triangular (j > i): only matters on the diagonal block
  if (bi == bj) bits = (lane == 63) ? 0ull : (bits & (~0ull << (lane + 1)));
  masks[((size_t)set * NROWS + i) * NW + bj] = bits;
}

// ---------------------------------------------------------------------------
// Stage 2: greedy scan. grid = 2 workgroups (one per set) x 1024 threads.
// Thread t: column word w = t&127, row subgroup g = t>>7 (8 rows/step).
// Retimed pipeline, ONE lgkm-barrier per step:
//   step b:  all waves OR kept(b-1) [published at step b-1, parity slot]
//            into sup[w] for w > b  (w==b untouched -> no race with wave0);
//            wave0 concurrently: cur = sup[b] (kept blocks <= b-2)
//                                | OR_{r in kept(b-1), sdiag_r != 0} sdiag_r
//            (sdiag_r = masks[64(b-1)+r][b], lane-distributed, prefetched),
//            then ballot-pruned ctz resolve with diag(b), publish kw.
// Invariant: sup[x] never read after step x, and OR at step b only touches
// w > b, so sup[b]'s missing kept(b-1) term is exactly wave0's correction.
// Row-mask loads prefetched distance-3 into 4 rotating reg buffers.
// ---------------------------------------------------------------------------
__global__ __launch_bounds__(1024) void nms_scan_kernel(
    const unsigned long long* __restrict__ masks,
    unsigned long long* __restrict__ keep)
{
  const int set = blockIdx.x;
  const unsigned long long* m = masks + (size_t)set * NROWS * NW;
  unsigned long long* kout = keep + set * NW;

  __shared__ unsigned long long sup[NW];
  __shared__ unsigned long long kw_sh[2];   // parity: slot b&1 = kept(b)

  const int t = threadIdx.x;
  const int w = t & 127;        // column word owned
  const int g = t >> 7;         // row subgroup (8 rows/step)
  const int lane = t & 63;
  const bool wave0 = (t < 64);

  if (t < NW) sup[t] = 0ull;
  if (t < 2)  kw_sh[t] = 0ull;

  // wave0 prefetch (distance 2): diag(b) = m[64b+lane][b],
  // sdiag(b) = m[64(b-1)+lane][b]  (block b-1's word-b column; 0 for b=0)
  unsigned long long d0 = 0ull, d1 = 0ull, sd0 = 0ull, sd1 = 0ull;
  if (wave0) {
    d0  = m[(size_t)(0 * 64 + lane) * NW + 0];
    d1  = m[(size_t)(1 * 64 + lane) * NW + 1];
    sd0 = 0ull;                                   // no block -1
    sd1 = m[(size_t)(0 * 64 + lane) * NW + 1];
  }

  // OR-phase buffers, distance-3: fill@step b loads block b+2, consumed at
  // step b+3 (step s consumes block s-1, guard w > s).
  unsigned long long bufA[8], bufB[8], bufC[8], bufD[8];
  if (w > 1) {  // block 0, consumed at step 1
    #pragma unroll
    for (int k = 0; k < 8; ++k) bufA[k] = m[(size_t)(0 * 64 + g * 8 + k) * NW + w];
  }
  if (w > 2) {  // block 1, consumed at step 2
    #pragma unroll
    for (int k = 0; k < 8; ++k) bufB[k] = m[(size_t)(1 * 64 + g * 8 + k) * NW + w];
  }

  wg_barrier_lds();

#define SCAN_STEP(B, CONS, FILL)                                              \
  {                                                                           \
    const int b = (B);                                                        \
    if (b < NB) {                                                             \
      /* kept(b-1), published at step b-1 into slot (b-1)&1 == (b+1)&1 */     \
      const unsigned long long kwv = kw_sh[(b + 1) & 1];                      \
      /* fill block b+2 (consumed at step b+3, guard w > b+3) */              \
      if (b + 2 < NB && w > b + 3) {                                          \
        _Pragma("unroll")                                                     \
        for (int k = 0; k < 8; ++k)                                           \
          FILL[k] = m[(size_t)((b + 2) * 64 + g * 8 + k) * NW + w];           \
      }                                                                       \
      if (wave0) {                                                            \
        unsigned long long dn = 0ull, sn = 0ull;                              \
        if (b + 2 < NB) {                                                     \
          dn = m[(size_t)((b + 2) * 64 + lane) * NW + (b + 2)];               \
          sn = m[(size_t)((b + 1) * 64 + lane) * NW + (b + 2)];               \
        }                                                                     \
        /* correction: kept(b-1) rows' word-b contributions (superdiag) */    \
        unsigned long long corr = 0ull;                                       \
        unsigned long long csel = __ballot(sd0 != 0ull) & kwv;                \
        while (csel) {                                                        \
          const int ii = __builtin_ctzll(csel);                               \
          corr |= rl64_dyn(sd0, ii);                                          \
          csel &= csel - 1ull;                                                \
        }                                                                     \
        unsigned long long cur = rfl64(sup[b]) | corr;                        \
        const unsigned long long nz = __ballot(d0 != 0ull);                   \
        unsigned long long alive = ~cur, kw = 0ull;                           \
        while (true) {                                                        \
          const unsigned long long cand = alive & nz;                         \
          if (!cand) { kw |= alive; break; }                                  \
          const int ii = __builtin_ctzll(cand);                               \
          const unsigned long long bit = 1ull << ii;                          \
          kw |= (alive & (bit - 1ull)) | bit;                                 \
          const unsigned long long d = rl64_dyn(d0, ii);                      \
          alive &= ~(d | bit | (bit - 1ull));                                 \
        }                                                                     \
        if (lane == 0) { kw_sh[b & 1] = kw; kout[b] = kw; }                   \
        d0 = d1; d1 = dn; sd0 = sd1; sd1 = sn;                                \
      }                                                                       \
      /* OR kept(b-1) into words w > b (w==b skipped -> no race) */           \
      if (b >= 1 && w > b) {                                                  \
        unsigned long long acc = 0ull;                                        \
        _Pragma("unroll")                                                     \
        for (int k = 0; k < 8; ++k)                                           \
          if ((kwv >> (g * 8 + k)) & 1ull) acc |= CONS[k];                    \
        if (acc) atomicOr(&sup[w], acc);                                      \
      }                                                                       \
      wg_barrier_lds();                                                       \
    }                                                                         \
  }

  // step 0: no consume, fills block 2 into bufC
  SCAN_STEP(0, bufD, bufC)
  // steps 1..127 (consume cycles A,B,C,D; fill cycles D,A,B,C); step 128
  // (last round, 4th slot) is skipped by the b < NB guard.
  for (int s = 1; s < NB; s += 4) {
    SCAN_STEP(s + 0, bufA, bufD)
    SCAN_STEP(s + 1, bufB, bufA)
    SCAN_STEP(s + 2, bufC, bufB)
    SCAN_STEP(s + 3, bufD, bufC)
  }
#undef SCAN_STEP
}

// ---------------------------------------------------------------------------
// Stage 3: epilogue. One thread per row: argmax(scores 5..8, first-max like
// jnp.argmax) + keep bits -> three masked outputs.
// ---------------------------------------------------------------------------
__global__ __launch_bounds__(256) void epilogue_kernel(
    const float* __restrict__ det, const float* __restrict__ rpn,
    const unsigned long long* __restrict__ keep, float* __restrict__ out)
{
  const int i = blockIdx.x * 256 + threadIdx.x;
  if (i >= NROWS) return;
  const bool kd = (keep[i >> 6]        >> (i & 63)) & 1ull;
  const bool kr = (keep[NW + (i >> 6)] >> (i & 63)) & 1ull;

  const float* p = det + (size_t)i * 9;
  const float sc0 = p[5], sc1 = p[6], sc2 = p[7], sc3 = p[8];
  int am = 0; float best = sc0;
  if (sc1 > best) { best = sc1; am = 1; }
  if (sc2 > best) { best = sc2; am = 2; }
  if (sc3 > best) { best = sc3; am = 3; }

  const float vm = (kd && am != 0) ? 1.0f : 0.0f;
  const float im = (kd && am == 0) ? 1.0f : 0.0f;
  float* o0 = out + (size_t)i * 9;
  float* o1 = out + (size_t)NROWS * 9 + (size_t)i * 9;
  #pragma unroll
  for (int c = 0; c < 9; ++c) { const float v = p[c]; o0[c] = v * vm; o1[c] = v * im; }

  const float rm = kr ? 1.0f : 0.0f;
  const float* q = rpn + (size_t)i * 6;
  float* o2 = out + (size_t)NROWS * 18 + (size_t)i * 6;
  #pragma unroll
  for (int c = 0; c < 6; ++c) o2[c] = q[c] * rm;
}

// ---------------------------------------------------------------------------
extern "C" void kernel_launch(void* const* d_in, const int* in_sizes, int n_in,
                              void* d_out, int out_size, void* d_ws, size_t ws_size,
                              hipStream_t stream)
{
  const float* det = (const float*)d_in[0];   // 8192 x 9 fp32
  const float* rpn = (const float*)d_in[1];   // 8192 x 6 fp32
  float* out = (float*)d_out;                 // 8192*9 + 8192*9 + 8192*6 fp32

  // workspace layout: [2][8192][128] u64 masks (16 MiB) + [2][128] u64 keep
  unsigned long long* masks = (unsigned long long*)d_ws;
  unsigned long long* keep  = masks + (size_t)2 * NROWS * NW;

  dim3 g1(NW, NW / 4, 2);
  nms_mask_kernel<<<g1, 256, 0, stream>>>(det, rpn, masks);
  nms_scan_kernel<<<2, 1024, 0, stream>>>(masks, keep);
  epilogue_kernel<<<(NROWS + 255) / 256, 256, 0, stream>>>(det, rpn, keep, out);
}

// Round 6
// 100.854 us; speedup vs baseline: 8.9749x; 2.5554x over previous
//
#include <hip/hip_runtime.h>

// Pipeline_8400956031319: dual greedy NMS (8192 det + 8192 rpn, IOU>0.6,
// index order) + argmax masking.
//
// R5 insight: the suppression graph is SPARSE (~1-4k edges of 33.5M pairs),
// and the dense-bitmask sequential scan was stuck at ~156us (128 serialized
// LDS/barrier round-trips at throttled clock). New structure:
//   Stage 0: zero edge counters.
//   Stage 1: IOU kernel emits packed edge list (i<<13|j, i<j, iou>0.6)
//            via atomicAdd append. No 8MB mask writes.
//   Stage 2: Jacobi fixpoint of keep[j] = !(exists i<j edge with keep[i])
//            — unique fixpoint == greedy NMS (well-founded recursion);
//            iterate until no change (sound: F(x)==x => THE fixpoint).
//            One workgroup per set, keep bits in LDS, ~5 rounds.
//   Stage 3: epilogue applies keep bits + score argmax to 3 outputs.

constexpr int NROWS    = 8192;
constexpr int NKW      = 256;              // keep words (u32) per set
constexpr unsigned EDGE_CAP = 1536u * 1024u;  // per set; ~400x margin
#define IOU_T 0.6f

// ws layout (bytes):
//   [0,   64)                      2x u32 edge counters (+pad)
//   [64,  64 + 4*CAP)              edges set0 (packed u32: i<<13|j)
//   [...,      + 4*CAP)            edges set1
//   [...,      + 2*NKW*4)          keep bits: [2][256] u32
// total ~12.3 MB (R5 used 16 MB fine).

// ---------------------------------------------------------------------------
__global__ __launch_bounds__(64) void init_kernel(unsigned* __restrict__ cnt)
{
  if (threadIdx.x < 2) cnt[threadIdx.x] = 0u;
}

// ---------------------------------------------------------------------------
// Stage 1: edge extraction. grid = (128 colblk, 32 rowblk4, 2 set),
// 256 threads = 4 row-waves sharing one 64-col tile in LDS.
// Upper-triangular tiles only; diagonal tile restricted to j > i.
// IOU arithmetic mirrors the reference fp32 expression exactly (IEEE div,
// same op order) so the edge set matches the reference bit-for-bit.
// Overlap pruning exact: inter==0 -> iou==0 -> no edge.
// ---------------------------------------------------------------------------
__global__ __launch_bounds__(256) void edge_kernel(
    const float* __restrict__ det, const float* __restrict__ rpn,
    unsigned* __restrict__ cnt, unsigned* __restrict__ edges)
{
  const int bj = blockIdx.x, bi4 = blockIdx.y, set = blockIdx.z;
  if (bj < bi4 * 4) return;                 // whole block lower-triangular
  const int t = threadIdx.x;
  const int wv = t >> 6, lane = t & 63;
  const int bi = bi4 * 4 + wv;

  const float* src  = (set == 0) ? det : rpn;
  const int    strd = (set == 0) ? 9 : 6;

  __shared__ float4 cb[64];
  __shared__ float  cbA[64];
  if (t < 64) {
    const float* q = src + (size_t)(bj * 64 + t) * strd + 1;
    const float4 v = make_float4(q[0], q[1], q[2], q[3]);
    cb[t]  = v;
    cbA[t] = fmaxf(v.z - v.x, 0.0f) * fmaxf(v.w - v.y, 0.0f);
  }
  __syncthreads();
  if (bj < bi) return;                      // wave-uniform partial skip

  const int i = bi * 64 + lane;
  const float* p = src + (size_t)i * strd + 1;
  const float x1 = p[0], y1 = p[1], x2 = p[2], y2 = p[3];
  const float ai = fmaxf(x2 - x1, 0.0f) * fmaxf(y2 - y1, 0.0f);

  unsigned long long bits = 0ull;
  #pragma unroll 4
  for (int c = 0; c < 64; ++c) {
    const float4 b = cb[c];
    const float ix1 = fmaxf(x1, b.x), iy1 = fmaxf(y1, b.y);
    const float ix2 = fminf(x2, b.z), iy2 = fminf(y2, b.w);
    const float inter = fmaxf(ix2 - ix1, 0.0f) * fmaxf(iy2 - iy1, 0.0f);
    if (__any(inter > 0.0f)) {              // ~75-80% of columns skip the div
      const float uni = ai + cbA[c] - inter;           // same order as ref
      const float iou = inter / fmaxf(uni, 1e-9f);     // same expr as ref
      if (iou > IOU_T) bits |= (1ull << c);
    }
  }
  // strict j > i on the diagonal tile
  if (bi == bj) bits = (lane == 63) ? 0ull : (bits & (~0ull << (lane + 1)));

  // emit edges (rare: ~3k total per set)
  unsigned* ebase = edges + (size_t)set * EDGE_CAP;
  while (bits) {
    const int c = __builtin_ctzll(bits);
    bits &= bits - 1ull;
    const unsigned j = (unsigned)(bj * 64 + c);
    const unsigned idx = atomicAdd(&cnt[set], 1u);
    if (idx < EDGE_CAP) ebase[idx] = ((unsigned)i << 13) | j;
  }
}

// ---------------------------------------------------------------------------
// Stage 2: Jacobi fixpoint. grid = 2 workgroups x 1024 threads.
// keep^{t+1}[j] = !(exists edge (i,j) with keep^t[i]). Double-buffered u32
// keep words in LDS; iterate until a round changes nothing (then it IS the
// unique fixpoint = greedy NMS result). Edges read from global (L2-hot).
// ---------------------------------------------------------------------------
__global__ __launch_bounds__(1024) void fixpoint_kernel(
    const unsigned* __restrict__ cnt, const unsigned* __restrict__ edges,
    unsigned* __restrict__ keep)
{
  const int set = blockIdx.x;
  const unsigned E = min(cnt[set], EDGE_CAP);
  const unsigned* eds = edges + (size_t)set * EDGE_CAP;
  unsigned* kout = keep + set * NKW;

  __shared__ unsigned kbuf[2][NKW];
  __shared__ int changed;

  const int t = threadIdx.x;
  if (t < NKW) kbuf[0][t] = 0xFFFFFFFFu;
  __syncthreads();

  int cur = 0;
  for (int round = 0; round < NROWS + 2; ++round) {
    const int nxt = cur ^ 1;
    if (t == 0) changed = 0;
    if (t < NKW) kbuf[nxt][t] = 0xFFFFFFFFu;
    __syncthreads();

    for (unsigned e = t; e < E; e += 1024) {
      const unsigned pk = eds[e];
      const unsigned i = pk >> 13, j = pk & 8191u;
      if ((kbuf[cur][i >> 5] >> (i & 31)) & 1u)
        atomicAnd(&kbuf[nxt][j >> 5], ~(1u << (j & 31)));
    }
    __syncthreads();

    if (t < NKW && kbuf[nxt][t] != kbuf[cur][t]) changed = 1;
    __syncthreads();

    cur = nxt;
    if (!changed) break;      // F(x)==x -> unique fixpoint reached
  }

  if (t < NKW) kout[t] = kbuf[cur][t];
}

// ---------------------------------------------------------------------------
// Stage 3: epilogue. One thread per row: argmax(scores 5..8, first-max like
// jnp.argmax) + keep bits -> three masked outputs.
// ---------------------------------------------------------------------------
__global__ __launch_bounds__(256) void epilogue_kernel(
    const float* __restrict__ det, const float* __restrict__ rpn,
    const unsigned* __restrict__ keep, float* __restrict__ out)
{
  const int i = blockIdx.x * 256 + threadIdx.x;
  if (i >= NROWS) return;
  const bool kd = (keep[i >> 5]       >> (i & 31)) & 1u;
  const bool kr = (keep[NKW + (i >> 5)] >> (i & 31)) & 1u;

  const float* p = det + (size_t)i * 9;
  const float sc0 = p[5], sc1 = p[6], sc2 = p[7], sc3 = p[8];
  int am = 0; float best = sc0;
  if (sc1 > best) { best = sc1; am = 1; }
  if (sc2 > best) { best = sc2; am = 2; }
  if (sc3 > best) { best = sc3; am = 3; }

  const float vm = (kd && am != 0) ? 1.0f : 0.0f;
  const float im = (kd && am == 0) ? 1.0f : 0.0f;
  float* o0 = out + (size_t)i * 9;
  float* o1 = out + (size_t)NROWS * 9 + (size_t)i * 9;
  #pragma unroll
  for (int c = 0; c < 9; ++c) { const float v = p[c]; o0[c] = v * vm; o1[c] = v * im; }

  const float rm = kr ? 1.0f : 0.0f;
  const float* q = rpn + (size_t)i * 6;
  float* o2 = out + (size_t)NROWS * 18 + (size_t)i * 6;
  #pragma unroll
  for (int c = 0; c < 6; ++c) o2[c] = q[c] * rm;
}

// ---------------------------------------------------------------------------
extern "C" void kernel_launch(void* const* d_in, const int* in_sizes, int n_in,
                              void* d_out, int out_size, void* d_ws, size_t ws_size,
                              hipStream_t stream)
{
  const float* det = (const float*)d_in[0];   // 8192 x 9 fp32
  const float* rpn = (const float*)d_in[1];   // 8192 x 6 fp32
  float* out = (float*)d_out;                 // 8192*9 + 8192*9 + 8192*6 fp32

  unsigned* cnt   = (unsigned*)d_ws;                        // 2 counters
  unsigned* edges = (unsigned*)((char*)d_ws + 64);          // 2 x CAP u32
  unsigned* keep  = edges + (size_t)2 * EDGE_CAP;           // 2 x 256 u32

  init_kernel<<<1, 64, 0, stream>>>(cnt);
  dim3 g1(128, 32, 2);
  edge_kernel<<<g1, 256, 0, stream>>>(det, rpn, cnt, edges);
  fixpoint_kernel<<<2, 1024, 0, stream>>>(cnt, edges, keep);
  epilogue_kernel<<<(NROWS + 255) / 256, 256, 0, stream>>>(det, rpn, keep, out);
}